// Round 11
// baseline (230.936 us; speedup 1.0000x reference)
//
#include <hip/hip_runtime.h>

// CvT block, MI355X bf16-MFMA implementation.
// B=32, C=128, L=32 (seq=1024), H=8, DK=64, HD=512, NLAYER=4.
// R11: attn occupancy 2->4 waves/SIMD: (a) K/V staged via async
// global_load_lds (width=16) double-buffer -- no prefetch VGPRs, no
// ds_write issue, barrier vmcnt-drain doubles as the DMA fence;
// (b) 2 query-tiles/wave (128q/WG, grid 2048) halves accumulator AGPRs.
// launch_bounds(256,4). Rest = R10 (transposed attn, register P, f32
// circulant bias as MFMA C operand, trunc-pack).

#define NB   32
#define NH   8
#define SEQ  1024
#define DKH  64
#define HDIM 512
#define CIN  128

// 0.125 * log2(e): folded into Wq and bias so scores are in exp2 domain.
#define SCL 0.18033688011112042f

typedef __bf16 bf16x8 __attribute__((ext_vector_type(8)));
typedef float floatx4 __attribute__((ext_vector_type(4)));
typedef unsigned short u16x8 __attribute__((ext_vector_type(8)));
typedef unsigned int uintx4 __attribute__((ext_vector_type(4)));

__device__ __forceinline__ unsigned short f2bf(float f) {
    union { float f; unsigned int u; } c; c.f = f;
    unsigned int u = c.u;
    return (unsigned short)((u + 0x7fffu + ((u >> 16) & 1u)) >> 16); // RNE
}
__device__ __forceinline__ bf16x8 ldfrag(const unsigned short* p) {
    u16x8 v = *reinterpret_cast<const u16x8*>(p);
    return __builtin_bit_cast(bf16x8, v);
}
// pack two f32 -> two RNE bf16; 'a' lands in the LOW short.
__device__ __forceinline__ unsigned int pkbf(float a, float b) {
    unsigned int ua = __builtin_bit_cast(unsigned int, a);
    unsigned int ub = __builtin_bit_cast(unsigned int, b);
    ua += 0x7fffu + ((ua >> 16) & 1u);
    ub += 0x7fffu + ((ub >> 16) & 1u);
    return __builtin_amdgcn_perm(ub, ua, 0x07060302u);
}
// truncation pack (P>0): one v_perm, no rounding adds.
__device__ __forceinline__ unsigned int pkbf_t(float a, float b) {
    return __builtin_amdgcn_perm(__builtin_bit_cast(unsigned int, b),
                                 __builtin_bit_cast(unsigned int, a), 0x07060302u);
}
// async global->LDS DMA, 16B/lane; lds dest = wave-uniform base + lane*16.
__device__ __forceinline__ void dma16(const unsigned short* g, unsigned short* l) {
    __builtin_amdgcn_global_load_lds(
        (const __attribute__((address_space(1))) unsigned int*)g,
        (__attribute__((address_space(3))) unsigned int*)l, 16, 0, 0);
}

// Fragment-order storage: 512-elem block = one wave fragment [lane][j].
// Kf (A-frag, m=key): frag (s,c): lane (q,n) j <-> K[key=16s+n][d=32c+8q+j]
// Vf (A-frag, m=d, permuted k): frag (u,c): lane (q,n) jj <->
//     V[key = 32c+16(jj>>2)+4q+(jj&3)][d=16u+n]   (matches P^T pack order)

// ---------------- prep: weights + compressed circulant bias ----------------
__global__ __launch_bounds__(256) void prep_wb(const float* __restrict__ Wq,
                                               const float* __restrict__ Wk,
                                               const float* __restrict__ Wv,
                                               const float* __restrict__ W0,
                                               const float* __restrict__ R,
                                               unsigned short* __restrict__ w2,
                                               unsigned short* __restrict__ w0f,
                                               float* __restrict__ biasG) {
    if (blockIdx.x < 256) {
        int gidx = blockIdx.x * 256 + threadIdx.x;       // [0, 65536)
        int lane = gidx & 63, slot = gidx >> 6;          // slot in [0, 1024)
        int bb = slot & 1, a = (slot >> 1) & 1, dxx = (slot >> 2) & 31, h = slot >> 7;
        int q = lane >> 4, n = lane & 15;
        int iy = (a << 4) + n;
        const float* Rh = R + (h << 10) + (dxx << 5);
        floatx4 v;
        for (int r = 0; r < 4; ++r) {
            int jy = (bb << 4) + 4 * q + r;
            v[r] = Rh[(iy - jy) & 31] * SCL;
        }
        *(floatx4*)&biasG[(size_t)gidx * 4] = v;
    } else {
        int idx = (blockIdx.x - 256) * 256 + threadIdx.x;  // [0, 262144)
        if (idx < 196608) {
            int row = idx >> 7, col = idx & 127;
            float v;
            if (row < 512)       v = Wq[idx] * SCL;
            else if (row < 1024) v = Wk[idx - 65536];
            else                 v = Wv[idx - 131072];
            int rt = row >> 4, nr = row & 15, kc = col >> 5, qc = (col & 31) >> 3, jc = col & 7;
            w2[((rt * 4 + kc) * 512) + (qc * 16 + nr) * 8 + jc] = f2bf(v);
        } else {
            int idx2 = idx - 196608;
            int row = idx2 >> 9, col = idx2 & 511;
            int rt = row >> 4, nr = row & 15, kcA = col >> 5, qc = (col & 31) >> 3, jc = col & 7;
            w0f[((rt * 16 + kcA) * 512) + (qc * 16 + nr) * 8 + jc] = f2bf(W0[idx2]);
        }
    }
}

// xt2: x transposed+scaled, in B/A fragment order over (b, pt=pos/16, kc=c/32).
__global__ __launch_bounds__(256) void prep_xt(const float* __restrict__ x,
                                               unsigned short* __restrict__ xt2) {
    __shared__ float lds[64 * 65];
    int b = blockIdx.x, c0 = blockIdx.y * 64, p0 = blockIdx.z * 64;
    int t = threadIdx.x, tr = t >> 6, tc = t & 63;
    const float inv_layer = 0.44721359549995793f;  // 1/sqrt(5)
    for (int rr = 0; rr < 16; ++rr) {
        int cl = rr * 4 + tr;
        lds[cl * 65 + tc] = x[(b * CIN + c0 + cl) * SEQ + p0 + tc];
    }
    __syncthreads();
    for (int rr = 0; rr < 16; ++rr) {
        int pl = rr * 4 + tr;
        int pos = p0 + pl, c = c0 + tc;
        int pt = pos >> 4, np = pos & 15, kc = c >> 5, qc = (c & 31) >> 3, jc = c & 7;
        xt2[((size_t)((b * 64 + pt) * 4 + kc) * 512) + (qc * 16 + np) * 8 + jc] =
            f2bf(lds[tc * 65 + pl] * inv_layer);
    }
}

// ---------------- fused QKV projection ----------------
__global__ __launch_bounds__(256, 4) void qkv_gemm(const unsigned short* __restrict__ xt2,
                                                   const unsigned short* __restrict__ w2,
                                                   unsigned short* __restrict__ Qt,
                                                   unsigned short* __restrict__ Kf,
                                                   unsigned short* __restrict__ Vf) {
    int b = blockIdx.x, y = blockIdx.y, zt = blockIdx.z;
    int tid = threadIdx.x, wave = tid >> 6, lane = tid & 63, q = lane >> 4, n = lane & 15;
    floatx4 acc[4];
    for (int s = 0; s < 4; ++s) acc[s] = (floatx4){0.f, 0.f, 0.f, 0.f};
    bf16x8 af[4], bfr[4][4];
    if (y < 16) {
        int rt = y * 4 + wave;                       // wrow tile
        const unsigned short* wbase = w2 + (size_t)rt * 4 * 512 + lane * 8;
        const unsigned short* xbase = xt2 + (size_t)(b * 64 + zt * 4) * 4 * 512 + lane * 8;
        for (int kc = 0; kc < 4; ++kc) af[kc] = ldfrag(wbase + kc * 512);
        for (int s = 0; s < 4; ++s)
            for (int kc = 0; kc < 4; ++kc) bfr[s][kc] = ldfrag(xbase + (s * 4 + kc) * 512);
        for (int kc = 0; kc < 4; ++kc)
            for (int s = 0; s < 4; ++s)
                acc[s] = __builtin_amdgcn_mfma_f32_16x16x32_bf16(af[kc], bfr[s][kc], acc[s], 0, 0, 0);
        int wrow0 = y * 64 + wave * 16;
        int pos0 = zt * 64;
        if (y < 8) {
            int h = wrow0 >> 6;
            int d0 = (wrow0 & 63) + 4 * q;
            for (int s = 0; s < 4; ++s) {
                uint2 pk;
                pk.x = pkbf(acc[s][0], acc[s][1]);
                pk.y = pkbf(acc[s][2], acc[s][3]);
                int pos = pos0 + 16 * s + n;
                *(uint2*)&Qt[((size_t)(b * NH + h) * SEQ + pos) * DKH + d0] = pk;
            }
        } else {
            // K: d = wave*16+4q+r (regs), key = 16s+n. A-frag store.
            int h = (wrow0 >> 6) - 8;
            int bh = b * NH + h;
            int cd = wave >> 1;
            int qk = 2 * (wave & 1) + (q >> 1);
            int jk = 4 * (q & 1);
            for (int s = 0; s < 4; ++s) {
                uint2 pk;
                pk.x = pkbf(acc[s][0], acc[s][1]);
                pk.y = pkbf(acc[s][2], acc[s][3]);
                size_t addr = ((size_t)(bh * 16 + zt) * 8 + s * 2 + cd) * 512
                              + (qk * 16 + n) * 8 + jk;
                *(uint2*)&Kf[addr] = pk;
            }
        }
    } else {
        int pt = zt * 4 + wave;                      // pos tile
        const unsigned short* xbase = xt2 + (size_t)((b * 64 + pt) * 4) * 512 + lane * 8;
        int rtv0 = 64 + (y - 16) * 4;                // V wrow tiles start at row 1024
        const unsigned short* wbase = w2 + (size_t)rtv0 * 4 * 512 + lane * 8;
        for (int kc = 0; kc < 4; ++kc) af[kc] = ldfrag(xbase + kc * 512);
        for (int s = 0; s < 4; ++s)
            for (int kc = 0; kc < 4; ++kc) bfr[s][kc] = ldfrag(wbase + (s * 4 + kc) * 512);
        for (int kc = 0; kc < 4; ++kc)
            for (int s = 0; s < 4; ++s)
                acc[s] = __builtin_amdgcn_mfma_f32_16x16x32_bf16(af[kc], bfr[s][kc], acc[s], 0, 0, 0);
        // V: key = wave*16+4q+r (regs) -> Vf A-frag with PV k-permutation.
        int vrow0 = (y - 16) * 64;
        int cj = wave >> 1;
        int jj0 = 4 * (wave & 1);
        for (int s = 0; s < 4; ++s) {
            int vrow = vrow0 + 16 * s + n;
            int h = vrow >> 6, d = vrow & 63;
            int u = d >> 4, nl = d & 15;
            uint2 pk;
            pk.x = pkbf(acc[s][0], acc[s][1]);
            pk.y = pkbf(acc[s][2], acc[s][3]);
            size_t addr = ((size_t)((b * NH + h) * 16 + zt) * 8 + u * 2 + cj) * 512
                          + (q * 16 + nl) * 8 + jj0;
            *(uint2*)&Vf[addr] = pk;
        }
    }
}

// ---------------- attention (transposed, register P, DMA dbuf) ----------------
// WG = 128 queries (4 waves x 2 query-tiles of 16); key tiles of 64.
// gid&255 = (b,h) -> one head per XCD (8 WGs/head share L2-resident Kf/Vf).
// K/V tiles DMA'd global->LDS (async, double buffer); ONE barrier per tile
// whose vmcnt-drain is the DMA completion fence. S^T = K Q^T with f32
// circulant bias as MFMA C operand; P^T trunc-packed in registers.
__global__ __launch_bounds__(256, 4) void attn_kernel(const unsigned short* __restrict__ Qt,
                                                      const unsigned short* __restrict__ Kf,
                                                      const unsigned short* __restrict__ Vf,
                                                      const float* __restrict__ biasG,
                                                      unsigned short* __restrict__ att2) {
    __shared__ alignas(16) unsigned short lds_k[2][8 * 512];   // A-frag K tiles
    __shared__ alignas(16) unsigned short lds_v[2][8 * 512];   // A-frag V tiles

    int gid = blockIdx.x;
    int bh = gid & 255, qb = gid >> 8;                 // qb in [0,8)
    int b = bh >> 3, h = bh & 7;
    int tid = threadIdx.x, wave = tid >> 6, lane = tid & 63, q = lane >> 4, n = lane & 15;
    int i0 = qb * 128 + wave * 32;
    int ti0 = i0 >> 4;

    const unsigned short* qbase = Qt + (size_t)bh * SEQ * DKH;
    const unsigned short* kft = Kf + (size_t)bh * 16 * 4096;
    const unsigned short* vft = Vf + (size_t)bh * 16 * 4096;
    const float* bGh = biasG + ((size_t)h * 32 * 4 * 256) + lane * 4;  // per-head + lane

    // Q as B-fragments: lane (q,n): query = i0+16qt+n, d = c*32+8q+j
    bf16x8 aq[2][2];
    for (int qt = 0; qt < 2; ++qt)
        for (int c = 0; c < 2; ++c)
            aq[qt][c] = ldfrag(qbase + (i0 + 16 * qt + n) * DKH + c * 32 + q * 8);

    // all-ones A fragment for column-sum MFMA (l = 1^T P^T)
    u16x8 ones_u;
    for (int t = 0; t < 8; ++t) ones_u[t] = 0x3F80;
    bf16x8 vone = __builtin_bit_cast(bf16x8, ones_u);

    floatx4 o[2][4], acc_l[2];
    for (int qt = 0; qt < 2; ++qt) {
        acc_l[qt] = (floatx4){0.f, 0.f, 0.f, 0.f};
        for (int u = 0; u < 4; ++u) o[qt][u] = (floatx4){0.f, 0.f, 0.f, 0.f};
    }

    int sb = wave * 1024;                              // this wave's staging slice (shorts)
    // DMA tile 0 into buffer 0 (2x1KB for K, 2x1KB for V per wave)
    dma16(kft + sb + lane * 8,        &lds_k[0][sb]);
    dma16(kft + sb + 512 + lane * 8,  &lds_k[0][sb + 512]);
    dma16(vft + sb + lane * 8,        &lds_v[0][sb]);
    dma16(vft + sb + 512 + lane * 8,  &lds_v[0][sb + 512]);
    __syncthreads();

    for (int kt = 0; kt < 16; ++kt) {
        int cur = kt & 1;
        if (kt < 15) {  // async DMA next tile into the other buffer
            int nxt = cur ^ 1;
            const unsigned short* kp = kft + (kt + 1) * 4096 + sb;
            const unsigned short* vp = vft + (kt + 1) * 4096 + sb;
            dma16(kp + lane * 8,       &lds_k[nxt][sb]);
            dma16(kp + 512 + lane * 8, &lds_k[nxt][sb + 512]);
            dma16(vp + lane * 8,       &lds_v[nxt][sb]);
            dma16(vp + 512 + lane * 8, &lds_v[nxt][sb + 512]);
        }

        // K fragments (shared across the 2 query tiles)
        bf16x8 kf2[4][2];
        for (int s = 0; s < 4; ++s)
            for (int c = 0; c < 2; ++c)
                kf2[s][c] = ldfrag(&lds_k[cur][(s * 2 + c) * 512 + lane * 8]);

        // S^T = K Q^T + bias^T (C-init); P^T = exp2 -> packed B-frags
        bf16x8 pf[2][2];
        for (int qt = 0; qt < 2; ++qt) {
            int tq = ti0 + qt;
            int a512 = (tq & 1) << 9;
            int e0 = (tq >> 1) - 2 * kt;
            floatx4 sv[4];
            for (int s = 0; s < 4; ++s) {
                int dxx = (e0 - (s >> 1)) & 31;
                floatx4 bsv = *(const floatx4*)(bGh + (dxx << 10) + a512 + ((s & 1) << 8));
                sv[s] = __builtin_amdgcn_mfma_f32_16x16x32_bf16(kf2[s][0], aq[qt][0], bsv, 0, 0, 0);
                sv[s] = __builtin_amdgcn_mfma_f32_16x16x32_bf16(kf2[s][1], aq[qt][1], sv[s], 0, 0, 0);
            }
            for (int c = 0; c < 2; ++c) {
                uintx4 pu;
                pu[0] = pkbf_t(__builtin_amdgcn_exp2f(sv[2 * c][0]), __builtin_amdgcn_exp2f(sv[2 * c][1]));
                pu[1] = pkbf_t(__builtin_amdgcn_exp2f(sv[2 * c][2]), __builtin_amdgcn_exp2f(sv[2 * c][3]));
                pu[2] = pkbf_t(__builtin_amdgcn_exp2f(sv[2 * c + 1][0]), __builtin_amdgcn_exp2f(sv[2 * c + 1][1]));
                pu[3] = pkbf_t(__builtin_amdgcn_exp2f(sv[2 * c + 1][2]), __builtin_amdgcn_exp2f(sv[2 * c + 1][3]));
                pf[qt][c] = __builtin_bit_cast(bf16x8, pu);
            }
        }

        // V fragments, then O^T += V^T P^T ; l += 1^T P^T
        bf16x8 vf2[4][2];
        for (int u = 0; u < 4; ++u)
            for (int c = 0; c < 2; ++c)
                vf2[u][c] = ldfrag(&lds_v[cur][(u * 2 + c) * 512 + lane * 8]);
        for (int qt = 0; qt < 2; ++qt) {
            acc_l[qt] = __builtin_amdgcn_mfma_f32_16x16x32_bf16(vone, pf[qt][0], acc_l[qt], 0, 0, 0);
            acc_l[qt] = __builtin_amdgcn_mfma_f32_16x16x32_bf16(vone, pf[qt][1], acc_l[qt], 0, 0, 0);
        }
        for (int u = 0; u < 4; ++u)
            for (int qt = 0; qt < 2; ++qt) {
                o[qt][u] = __builtin_amdgcn_mfma_f32_16x16x32_bf16(vf2[u][0], pf[qt][0], o[qt][u], 0, 0, 0);
                o[qt][u] = __builtin_amdgcn_mfma_f32_16x16x32_bf16(vf2[u][1], pf[qt][1], o[qt][u], 0, 0, 0);
            }

        // ONE barrier: waits DMA (vmcnt) + guards buffer swap
        __syncthreads();
    }

    // epilogue: O^T lane (q,n): query = i0+16qt+n, d = 16u+4q+r -> att2 A-frag
    for (int qt = 0; qt < 2; ++qt) {
        float inv = 1.0f / acc_l[qt][0];
        int pt = ti0 + qt;
        for (int u = 0; u < 4; ++u) {
            int kcA = 2 * h + (u >> 1);
            int q2 = 2 * (u & 1) + (q >> 1);
            uint2 pk;
            pk.x = pkbf(o[qt][u][0] * inv, o[qt][u][1] * inv);
            pk.y = pkbf(o[qt][u][2] * inv, o[qt][u][3] * inv);
            size_t addr = ((size_t)((b * 64 + pt) * 16 + kcA) * 512)
                          + (q2 * 16 + n) * 8 + 4 * (q & 1);
            *(uint2*)&att2[addr] = pk;
        }
    }
}

// ---------------- output projection + residual ----------------
__global__ __launch_bounds__(256, 4) void out_gemm(const unsigned short* __restrict__ att2,
                                                   const unsigned short* __restrict__ w0f,
                                                   const float* __restrict__ x,
                                                   float* __restrict__ out) {
    int b = blockIdx.x, ct = blockIdx.y, ptb = blockIdx.z;
    int tid = threadIdx.x, wave = tid >> 6, lane = tid & 63, q = lane >> 4, n = lane & 15;
    int pos0 = ptb * 64 + wave * 16;
    int c0 = ct * 64;
    int pt = ptb * 4 + wave;
    const unsigned short* abase = att2 + (size_t)(b * 64 + pt) * 16 * 512 + lane * 8;
    const unsigned short* wbase = w0f + (size_t)(c0 >> 4) * 16 * 512 + lane * 8;
    floatx4 acc[4];
    for (int s = 0; s < 4; ++s) acc[s] = (floatx4){0.f, 0.f, 0.f, 0.f};
    for (int g = 0; g < 4; ++g) {
        bf16x8 af[4], bfr[4][4];
        for (int k2 = 0; k2 < 4; ++k2) af[k2] = ldfrag(abase + (g * 4 + k2) * 512);
        for (int s = 0; s < 4; ++s)
            for (int k2 = 0; k2 < 4; ++k2)
                bfr[s][k2] = ldfrag(wbase + (s * 16 + g * 4 + k2) * 512);
        for (int k2 = 0; k2 < 4; ++k2)
            for (int s = 0; s < 4; ++s)
                acc[s] = __builtin_amdgcn_mfma_f32_16x16x32_bf16(af[k2], bfr[s][k2], acc[s], 0, 0, 0);
    }
    int p0q = pos0 + 4 * q;
    for (int s = 0; s < 4; ++s) {
        int c = c0 + 16 * s + n;
        size_t idx = ((size_t)b * CIN + c) * SEQ + p0q;
        floatx4 res = *(const floatx4*)&x[idx];
        floatx4 v = acc[s] + res;
        *(floatx4*)&out[idx] = v;
    }
}

// ---------------- launch ----------------
extern "C" void kernel_launch(void* const* d_in, const int* in_sizes, int n_in,
                              void* d_out, int out_size, void* d_ws, size_t ws_size,
                              hipStream_t stream) {
    const float* x  = (const float*)d_in[0];
    const float* Wq = (const float*)d_in[1];
    const float* Wk = (const float*)d_in[2];
    const float* Wv = (const float*)d_in[3];
    const float* R  = (const float*)d_in[4];
    const float* W0 = (const float*)d_in[5];
    float* out = (float*)d_out;

    char* ws = (char*)d_ws;
    size_t off = 0;
    unsigned short* Qt   = (unsigned short*)(ws + off); off += (size_t)NB * NH * SEQ * DKH * 2;
    unsigned short* Kf   = (unsigned short*)(ws + off); off += (size_t)NB * NH * SEQ * DKH * 2;
    unsigned short* Vf   = (unsigned short*)(ws + off); off += (size_t)NB * NH * SEQ * DKH * 2;
    unsigned short* att2 = (unsigned short*)(ws + off); off += (size_t)NB * SEQ * HDIM * 2;
    unsigned short* xt2  = (unsigned short*)(ws + off); off += (size_t)NB * SEQ * CIN * 2;
    unsigned short* w2   = (unsigned short*)(ws + off); off += (size_t)1536 * 128 * 2;
    unsigned short* w0f  = (unsigned short*)(ws + off); off += (size_t)128 * 512 * 2;
    float* biasG = (float*)(ws + off); off += (size_t)NH * 32 * 4 * 256 * 4;   // 1 MB
    (void)ws_size; (void)in_sizes; (void)n_in; (void)out_size;

    prep_wb<<<1280, 256, 0, stream>>>(Wq, Wk, Wv, W0, R, w2, w0f, biasG);
    prep_xt<<<dim3(NB, 2, 16), 256, 0, stream>>>(x, xt2);
    qkv_gemm<<<dim3(NB, 24, 16), 256, 0, stream>>>(xt2, w2, Qt, Kf, Vf);
    attn_kernel<<<NB * NH * 8, 256, 0, stream>>>(Qt, Kf, Vf, biasG, att2);
    out_gemm<<<dim3(NB, 2, 16), 256, 0, stream>>>(att2, w0f, x, out);
}